// Round 6
// baseline (386.764 us; speedup 1.0000x reference)
//
#include <hip/hip_runtime.h>
#include <hip/hip_bf16.h>

#define M_LEN 1024
#define BATCH 16384

// fallback kernel tiling
#define BM 128
#define BN 128
#define BK 64
#define THREADS 256

// main gemm tiling (256x128, BK=32, 8 waves of 64x64, 2 blocks/CU)
#define BM3 256
#define BN3 128
#define BK3 32
#define GTHREADS 512

typedef __attribute__((ext_vector_type(8))) short bf16x8;
typedef __attribute__((ext_vector_type(4))) float f32x4;
typedef unsigned short ushort_t;

// ---------------- helpers ----------------

// fp32 -> bf16 RNE
__device__ __forceinline__ ushort_t bf16_rne(float f) {
    unsigned u = __float_as_uint(f);
    unsigned r = u + 0x7FFFu + ((u >> 16) & 1u);
    return (ushort_t)(r >> 16);
}

__device__ __forceinline__ float bf16_to_f(ushort_t u) {
    return __uint_as_float(((unsigned)u) << 16);
}

// pack two fp32 -> two bf16 (RTZ) in one v_perm_b32 (fallback kernel only)
__device__ __forceinline__ unsigned pack2(float lo, float hi) {
    return __builtin_amdgcn_perm(__float_as_uint(hi), __float_as_uint(lo), 0x07060302u);
}

// async global->LDS, 16B per lane. LDS dest is wave-uniform base + lane*16.
__device__ __forceinline__ void gload_lds16(const void* g, void* l) {
    __builtin_amdgcn_global_load_lds(
        (const __attribute__((address_space(1))) unsigned int*)g,
        (__attribute__((address_space(3))) unsigned int*)l,
        16, 0, 0);
}

// non-temporal 16B load
__device__ __forceinline__ float4 ntload4(const float4* p) {
    f32x4 v = __builtin_nontemporal_load((const f32x4*)p);
    return make_float4(v.x, v.y, v.z, v.w);
}

// ---------------- pass 1: fp32 -> bf16 conversion + zero-row flags ----------------
// ~83 us, at its streaming roofline — unchanged since R0.
__global__ __launch_bounds__(THREADS) void convert_pass(
    const float* __restrict__ mod0, const float* __restrict__ mod1,
    const float* __restrict__ mod2, const float* __restrict__ mod3,
    const float* __restrict__ W,
    ushort_t* __restrict__ Ab, ushort_t* __restrict__ Wb, int* __restrict__ zf)
{
    const int blk  = blockIdx.x;
    const int wave = threadIdx.x >> 6;
    const int lane = threadIdx.x & 63;

    if (blk < BATCH) {
        const int b = blk, m = wave;
        const float* mp = (m == 0) ? mod0 : (m == 1) ? mod1 : (m == 2) ? mod2 : mod3;
        const float4* row = (const float4*)(mp + (size_t)b * M_LEN);
        ushort_t* dst = Ab + ((size_t)b * 4 + m) * M_LEN;
        unsigned orr = 0u;
        #pragma unroll
        for (int j = 0; j < 4; ++j) {
            float4 v = ntload4(&row[j * 64 + lane]);
            orr |= (__float_as_uint(v.x) | __float_as_uint(v.y) |
                    __float_as_uint(v.z) | __float_as_uint(v.w)) << 1;  // drop signs
            ushort4 o;
            o.x = bf16_rne(v.x); o.y = bf16_rne(v.y);
            o.z = bf16_rne(v.z); o.w = bf16_rne(v.w);
            ((ushort4*)dst)[j * 64 + lane] = o;
        }
        const int nz = __any(orr != 0u);
        if (lane == 0) zf[b * 4 + m] = nz ? 0 : 1;
    } else {
        const int r = (blk - BATCH) * 4 + wave;
        const float4* row = (const float4*)(W + (size_t)r * M_LEN);
        ushort_t* dst = Wb + (size_t)r * M_LEN;
        #pragma unroll
        for (int j = 0; j < 4; ++j) {
            float4 v = row[j * 64 + lane];
            ushort4 o;
            o.x = bf16_rne(v.x); o.y = bf16_rne(v.y);
            o.z = bf16_rne(v.z); o.w = bf16_rne(v.w);
            ((ushort4*)dst)[j * 64 + lane] = o;
        }
    }
}

// ---------------- pass 2: 256x128 GEMM, counted-vmcnt dbuf + 2 blocks/CU --------
// Round-6 theory: R0/R3/R5 all plateau at 176-191 us / 33% MfmaUtil across three
// different schedules; common factor = 1 barrier-group/CU (R3/R5: 1 block/CU) or
// no pipeline (R0). This kernel combines BOTH overlap mechanisms:
//  - in-block: R3's verified 2-deep counted-vmcnt dbuf (3 loads/tile, vmcnt(3))
//  - cross-block: 48 KB LDS + 64-reg accumulator (64x64/wave) + lb(512,4)
//    -> 2 independent blocks/CU, 4 waves/SIMD; one block's MFMA fills the
//    other's barrier/vmcnt stalls (m114 mechanism, absent in R3/R5).
// Sync invariant (R3 verbatim, 3 loads/tile): at each tile-end barrier only the
// newest 3 VMEM ops (tile t+2's stage, issued after the post-compute barrier)
// may be outstanding; vmcnt(3) forces tile t+1's staging complete, barrier
// makes it collective. Stage targets the buffer whose readers finished at the
// immediately preceding barrier.
__global__ __launch_bounds__(GTHREADS, 4) void gemm_tlp(
    const ushort_t* __restrict__ Ab, const ushort_t* __restrict__ Wb,
    const int* __restrict__ zf, float* __restrict__ out)
{
    __shared__ __align__(16) ushort_t As0[BM3 * BK3];   // 16 KB
    __shared__ __align__(16) ushort_t As1[BM3 * BK3];   // 16 KB
    __shared__ __align__(16) ushort_t Bs0[BN3 * BK3];   // 8 KB
    __shared__ __align__(16) ushort_t Bs1[BN3 * BK3];   // 8 KB
    __shared__ float scalerS[BM3 / 4];                  // 64 patients

    const int t    = threadIdx.x;
    const int lane = t & 63;
    const int wave = t >> 6;          // 0..7
    const int quad = lane >> 4;
    const int ln15 = lane & 15;
    const int wm   = wave >> 1;       // 0..3 : rows wm*64..+64
    const int wn   = wave & 1;        // 0..1 : cols wn*64..+64

    // T1: XCD-aware bijective remap. 2048 blocks, 8 XCDs, 2048 % 8 == 0.
    const int bid  = blockIdx.x;
    const int wid  = (bid & 7) * 256 + (bid >> 3);
    const int colb = wid & 7;          // 8 col panels of 128
    const int rowb = wid >> 3;         // 256 row panels of 256
    const int row0 = rowb * BM3;
    const int col0 = colb * BN3;

    if (t < 64) {
        const int4 f = ((const int4*)zf)[rowb * 64 + t];
        const int z = f.x + f.y + f.z + f.w;
        scalerS[t] = (z > 0) ? (float)(z + 1) : 1.0f;
    }

    // ---- staging geometry (rows of 32 ushort = 64 B, 4 chunks of 16 B) ----
    // thread t covers row (t>>2) within an 8 KB round; LDS slot = lane&3
    // (linear dest via gload_lds), global chunk = (lane&3)^(row&3).
    const int rl = lane >> 2;          // 0..15
    const int c4 = (lane & 3) ^ (rl & 3);
    const ushort_t* aP[2];
    const ushort_t* bP;
    unsigned aD[2], bD;
    #pragma unroll
    for (int r = 0; r < 2; ++r) {
        const int arow = r * 128 + wave * 16 + rl;          // 0..255
        aP[r] = Ab + (size_t)(row0 + arow) * M_LEN + c4 * 8;
        aD[r] = (unsigned)((r * 128 + wave * 16) * BK3);    // ushort units
    }
    {
        const int brow = wave * 16 + rl;                    // 0..127
        bP = Wb + (size_t)(col0 + brow) * M_LEN + c4 * 8;
        bD = (unsigned)((wave * 16) * BK3);
    }

    // stage one K-tile (2 A rounds + 1 B round = 3 gload_lds16), advance ptrs
    #define STAGE(AD_, BD_)                                             \
        do {                                                            \
            gload_lds16(aP[0], (AD_) + aD[0]); aP[0] += BK3;            \
            gload_lds16(aP[1], (AD_) + aD[1]); aP[1] += BK3;            \
            gload_lds16(bP,    (BD_) + bD);    bP    += BK3;            \
        } while (0)

    f32x4 acc[4][4];
    #pragma unroll
    for (int i = 0; i < 4; ++i)
        #pragma unroll
        for (int j = 0; j < 4; ++j)
            acc[i][j] = (f32x4){0.f, 0.f, 0.f, 0.f};

    // reader: row rho, global chunk quad -> LDS slot quad^(rho&3)
    const unsigned slotOff = (unsigned)((quad ^ (ln15 & 3)) * 8);
    const unsigned aOff = (unsigned)((wm * 64 + ln15) * BK3) + slotOff;
    const unsigned bOff = (unsigned)((wn * 64 + ln15) * BK3) + slotOff;

    auto compute = [&](const ushort_t* As_, const ushort_t* Bs_) {
        bf16x8 af[4], bfr[4];
        #pragma unroll
        for (int j = 0; j < 4; ++j)
            bfr[j] = *(const bf16x8*)(&Bs_[bOff + j * 16 * BK3]);
        #pragma unroll
        for (int i = 0; i < 4; ++i)
            af[i] = *(const bf16x8*)(&As_[aOff + i * 16 * BK3]);
        __builtin_amdgcn_s_setprio(1);
        #pragma unroll
        for (int i = 0; i < 4; ++i)
            #pragma unroll
            for (int j = 0; j < 4; ++j)
                acc[i][j] = __builtin_amdgcn_mfma_f32_16x16x32_bf16(
                    af[i], bfr[j], acc[i][j], 0, 0, 0);
        __builtin_amdgcn_s_setprio(0);
    };

    // prologue: stage K0 -> buf0, K1 -> buf1; wait K0 (3 newest = K1 in flight);
    // lgkmcnt(0) also makes scalerS visible to all waves after the barrier.
    STAGE(As0, Bs0);
    STAGE(As1, Bs1);
    asm volatile("s_waitcnt vmcnt(3) lgkmcnt(0)" ::: "memory");
    __builtin_amdgcn_s_barrier();

    // steady state: 15 iterations x 2 K-tiles (K0..K29), staging K2..K31
    #pragma unroll 1
    for (int t2 = 0; t2 < 15; ++t2) {
        compute(As0, Bs0);                 // K-tile 2*t2
        __builtin_amdgcn_s_barrier();      // all waves done reading buf0
        STAGE(As0, Bs0);                   // K-tile 2*t2+2 -> buf0
        asm volatile("s_waitcnt vmcnt(3)" ::: "memory");   // 2*t2+1 landed
        __builtin_amdgcn_s_barrier();

        compute(As1, Bs1);                 // K-tile 2*t2+1
        __builtin_amdgcn_s_barrier();      // all waves done reading buf1
        STAGE(As1, Bs1);                   // K-tile 2*t2+3 -> buf1
        asm volatile("s_waitcnt vmcnt(3)" ::: "memory");   // 2*t2+2 landed
        __builtin_amdgcn_s_barrier();
    }
    // tail: K30 (landed: last loop wait left only K31's 3 outstanding)
    compute(As0, Bs0);
    asm volatile("s_waitcnt vmcnt(0)" ::: "memory");       // K31 landed
    __builtin_amdgcn_s_barrier();
    compute(As1, Bs1);

    // ---- epilogue: modality softmax + weighted sum + scaler, nt-store ----
    // C/D 16x16: col = ln15, row = quad*4 + reg; A rows (4b+m) -> reg == modality
    // (row0, wm*64, i*16, quad*4 all ≡ 0 mod 4).
    #pragma unroll
    for (int i = 0; i < 4; ++i) {
        const int bl = wm * 16 + i * 4 + quad;      // patient within block (0..63)
        const int b  = rowb * 64 + bl;
        const float scal = scalerS[bl];
        const ushort_t* xr = Ab + (size_t)b * 4 * M_LEN;   // row 4b (modality 0)
        #pragma unroll
        for (int j = 0; j < 4; ++j) {
            const int k = col0 + wn * 64 + j * 16 + ln15;
            const float x0 = bf16_to_f(xr[k]);
            const float x1 = bf16_to_f(xr[M_LEN + k]);
            const float x2 = bf16_to_f(xr[2 * M_LEN + k]);
            const float x3 = bf16_to_f(xr[3 * M_LEN + k]);
            const f32x4 s = acc[i][j];
            const float mx = fmaxf(fmaxf(s.x, s.y), fmaxf(s.z, s.w));
            const float e0 = __expf(s.x - mx);
            const float e1 = __expf(s.y - mx);
            const float e2 = __expf(s.z - mx);
            const float e3 = __expf(s.w - mx);
            const float num = e0 * x0 + e1 * x1 + e2 * x2 + e3 * x3;
            const float v = num * scal / (e0 + e1 + e2 + e3);
            __builtin_nontemporal_store(v, &out[(size_t)b * M_LEN + k]);
        }
    }
    #undef STAGE
}

// ---------------- fallback: single fused kernel (used if ws too small) ----------
__global__ __launch_bounds__(THREADS) void fused_modal_attn(
    const float* __restrict__ mod0, const float* __restrict__ mod1,
    const float* __restrict__ mod2, const float* __restrict__ mod3,
    const float* __restrict__ W, float* __restrict__ out)
{
    __shared__ __align__(16) unsigned short As[BM * BK];
    __shared__ __align__(16) unsigned short Bs[BN * BK];
    __shared__ unsigned rowOr[BM];
    __shared__ float scalerS[BM / 4];

    const int t    = threadIdx.x;
    const int lane = t & 63;
    const int wave = t >> 6;
    const int quad = lane >> 4;
    const int ln15 = lane & 15;
    const int wm   = wave >> 1;
    const int wn   = wave & 1;

    const int colb = blockIdx.x;
    const int rowb = blockIdx.y;
    const int row0 = rowb * BM;
    const int col0 = colb * BN;

    if (t < BM) rowOr[t] = 0u;

    const int sr  = t >> 3;
    const int scl = t & 7;

    const float* ap[4];
    const float* bp[4];
    unsigned ldsOff[4];
    unsigned orAcc[4] = {0u, 0u, 0u, 0u};
    #pragma unroll
    for (int j = 0; j < 4; ++j) {
        const int r  = j * 32 + sr;
        const int gr = row0 + r;
        const int b  = gr >> 2;
        const int m  = gr & 3;
        const float* mp = (m == 0) ? mod0 : (m == 1) ? mod1 : (m == 2) ? mod2 : mod3;
        ap[j] = mp + (size_t)b * M_LEN + scl * 8;
        bp[j] = W + (size_t)(col0 + r) * M_LEN + scl * 8;
        ldsOff[j] = (unsigned)(r * 64 + ((scl ^ (r & 7)) * 8));
    }

    f32x4 acc[4][4];
    #pragma unroll
    for (int i = 0; i < 4; ++i)
        #pragma unroll
        for (int j = 0; j < 4; ++j)
            acc[i][j] = (f32x4){0.f, 0.f, 0.f, 0.f};

    const unsigned slotB   = (unsigned)(quad ^ (ln15 & 7));
    const unsigned aRowOff = (unsigned)((wm * 64 + ln15) * 64);
    const unsigned bRowOff = (unsigned)((wn * 64 + ln15) * 64);

    for (int it = 0; it < 16; ++it) {
        __syncthreads();
        #pragma unroll
        for (int j = 0; j < 4; ++j) {
            const float4* pa = (const float4*)ap[j];
            const float4* pb = (const float4*)bp[j];
            float4 a0 = pa[0], a1 = pa[1];
            float4 b0 = pb[0], b1 = pb[1];
            ap[j] += BK; bp[j] += BK;

            unsigned pA0 = pack2(a0.x, a0.y), pA1 = pack2(a0.z, a0.w);
            unsigned pA2 = pack2(a1.x, a1.y), pA3 = pack2(a1.z, a1.w);
            orAcc[j] |= (pA0 | pA1) | (pA2 | pA3);
            *(uint4*)(&As[ldsOff[j]]) = make_uint4(pA0, pA1, pA2, pA3);

            unsigned pB0 = pack2(b0.x, b0.y), pB1 = pack2(b0.z, b0.w);
            unsigned pB2 = pack2(b1.x, b1.y), pB3 = pack2(b1.z, b1.w);
            *(uint4*)(&Bs[ldsOff[j]]) = make_uint4(pB0, pB1, pB2, pB3);
        }
        __syncthreads();
        #pragma unroll
        for (int ks = 0; ks < 2; ++ks) {
            const unsigned slot8 = (slotB ^ (unsigned)(ks * 4)) * 8u;
            bf16x8 af[4], bfr[4];
            #pragma unroll
            for (int i = 0; i < 4; ++i)
                af[i] = *(const bf16x8*)(&As[aRowOff + i * 1024 + slot8]);
            #pragma unroll
            for (int j = 0; j < 4; ++j)
                bfr[j] = *(const bf16x8*)(&Bs[bRowOff + j * 1024 + slot8]);
            #pragma unroll
            for (int i = 0; i < 4; ++i)
                #pragma unroll
                for (int j = 0; j < 4; ++j)
                    acc[i][j] = __builtin_amdgcn_mfma_f32_16x16x32_bf16(
                        af[i], bfr[j], acc[i][j], 0, 0, 0);
        }
    }

    #pragma unroll
    for (int j = 0; j < 4; ++j)
        atomicOr(&rowOr[j * 32 + sr], orAcc[j]);
    __syncthreads();
    if (t < 32) {
        const int z = (rowOr[4 * t + 0] == 0u) + (rowOr[4 * t + 1] == 0u)
                    + (rowOr[4 * t + 2] == 0u) + (rowOr[4 * t + 3] == 0u);
        scalerS[t] = (z > 0) ? (float)(z + 1) : 1.0f;
    }
    __syncthreads();

    #pragma unroll
    for (int i = 0; i < 4; ++i) {
        const int bl = wm * 16 + i * 4 + quad;
        const int b  = rowb * 32 + bl;
        const float scal = scalerS[bl];
        #pragma unroll
        for (int j = 0; j < 4; ++j) {
            const int k = col0 + wn * 64 + j * 16 + ln15;
            const size_t off = (size_t)b * M_LEN + k;
            const float x0 = mod0[off], x1 = mod1[off];
            const float x2 = mod2[off], x3 = mod3[off];
            const f32x4 s = acc[i][j];
            const float mx = fmaxf(fmaxf(s.x, s.y), fmaxf(s.z, s.w));
            const float e0 = __expf(s.x - mx);
            const float e1 = __expf(s.y - mx);
            const float e2 = __expf(s.z - mx);
            const float e3 = __expf(s.w - mx);
            const float num = e0 * x0 + e1 * x1 + e2 * x2 + e3 * x3;
            out[off] = num * scal / (e0 + e1 + e2 + e3);
        }
    }
}

// ---------------- launch ----------------
extern "C" void kernel_launch(void* const* d_in, const int* in_sizes, int n_in,
                              void* d_out, int out_size, void* d_ws, size_t ws_size,
                              hipStream_t stream) {
    const float* mod0 = (const float*)d_in[0];
    const float* mod1 = (const float*)d_in[1];
    const float* mod2 = (const float*)d_in[2];
    const float* mod3 = (const float*)d_in[3];
    const float* W    = (const float*)d_in[4];
    float* out = (float*)d_out;

    // workspace layout: A' bf16 (128 MiB) | W bf16 (2 MiB) | zf int[65536] (256 KiB)
    const size_t abBytes = (size_t)4 * BATCH * M_LEN * sizeof(ushort_t);
    const size_t wbBytes = (size_t)M_LEN * M_LEN * sizeof(ushort_t);
    const size_t zfBytes = (size_t)4 * BATCH * sizeof(int);
    const size_t need = abBytes + wbBytes + zfBytes;

    if (ws_size >= need) {
        ushort_t* Ab = (ushort_t*)d_ws;
        ushort_t* Wb = (ushort_t*)((char*)d_ws + abBytes);
        int*      zfp = (int*)((char*)d_ws + abBytes + wbBytes);

        convert_pass<<<dim3(BATCH + M_LEN / 4), dim3(THREADS), 0, stream>>>(
            mod0, mod1, mod2, mod3, W, Ab, Wb, zfp);

        // 2048 blocks (8 colb x 256 rowb), T1 swizzle inside the kernel
        gemm_tlp<<<dim3((M_LEN / BN3) * ((4 * BATCH) / BM3)), dim3(GTHREADS), 0, stream>>>(
            Ab, Wb, zfp, out);
    } else {
        dim3 grid(M_LEN / BN, (4 * BATCH) / BM);
        fused_modal_attn<<<grid, dim3(THREADS), 0, stream>>>(
            mod0, mod1, mod2, mod3, W, out);
    }
}